// Round 16
// baseline (238.245 us; speedup 1.0000x reference)
//
#include <hip/hip_runtime.h>
#include <math.h>

static constexpr int IMGS = 2;
static constexpr int H = 128, W = 128;
static constexpr int NP = H * W;           // 16384
static constexpr int KWIN = 30;            // quickshift window radius (ceil(3*10))
static constexpr int GR = 20;              // gaussian radius int(4*5+0.5)
static constexpr float INV = 0.005f;       // 0.5 / (10*10)
static constexpr int MAXSEG = 40;

// padded feature layout: row stride 192 float4, cols [30,158) hold the image.
// float4 = (L, a, b, dens); pads = (1e6,1e6,1e6,-inf).
static constexpr int PSTR = 192;
static constexpr int PIMG = H * PSTR;      // 24576 float4 per image

typedef float f32x2 __attribute__((ext_vector_type(2)));

// ---------------- prep: pf sentinel fill + rgb2lab into bufL -------------------
__global__ void k_prep(const float* __restrict__ x, float4* __restrict__ pf,
                       float4* __restrict__ bufL) {
#pragma clang fp contract(off)
  int i = blockIdx.x * blockDim.x + threadIdx.x;
  if (i < IMGS * PIMG) pf[i] = make_float4(1e6f, 1e6f, 1e6f, -__builtin_inff());
  if (i >= IMGS * NP) return;
  int img = i / NP, p = i % NP;
  const float* base = x + img * 3 * NP;
  float rgb[3] = { base[p], base[NP + p], base[2 * NP + p] };
  float lin[3];
  for (int c = 0; c < 3; ++c) {
    float v = rgb[c];
    lin[c] = (v > 0.04045f) ? powf((v + 0.055f) / 1.055f, 2.4f) : (v / 12.92f);
  }
  const float M[3][3] = {{0.412453f, 0.357580f, 0.180423f},
                         {0.212671f, 0.715160f, 0.072169f},
                         {0.019334f, 0.119193f, 0.950227f}};
  const float wp[3] = {0.95047f, 1.0f, 1.08883f};
  float f[3];
  for (int j = 0; j < 3; ++j) {
    float s = lin[0] * M[j][0];
    s = s + lin[1] * M[j][1];
    s = s + lin[2] * M[j][2];
    float xyz = s / wp[j];
    f[j] = (xyz > 0.008856f) ? cbrtf(fmaxf(xyz, 1e-8f))
                             : (7.787f * xyz + (float)(16.0 / 116.0));
  }
  float L = 116.0f * f[1] - 16.0f;
  float a = 500.0f * (f[0] - f[1]);
  float b = 200.0f * (f[1] - f[2]);
  bufL[i] = make_float4(L, a, b, 0.0f);
}

// ---------------- fused separable gaussian (V then H), symmetric pad -----------
__global__ __launch_bounds__(384)
void k_blur(const float4* __restrict__ bufL, float4* __restrict__ pf) {
#pragma clang fp contract(off)
  __shared__ float w[2 * GR + 1];
  __shared__ float mid[3][128];
  if (threadIdx.x == 0) {
    double k[2 * GR + 1];
    double s = 0.0;
    for (int i = -GR; i <= GR; ++i) {
      double t = (double)i / 5.0;
      double v = exp(-0.5 * t * t);
      k[i + GR] = v;
      s += v;
    }
    for (int i = 0; i < 2 * GR + 1; ++i) w[i] = (float)(k[i] / s);
  }
  __syncthreads();
  int tid = threadIdx.x;
  int c = tid >> 7;                         // 0..2
  int xx = tid & 127;
  int b = blockIdx.x;                       // img*128 + y
  int y = b & 127, img = b >> 7;
  const float* base = (const float*)(bufL + img * NP);
  float a = 0.0f;
  for (int t = 0; t <= 2 * GR; ++t) {
    int yy = y - GR + t;
    if (yy < 0) yy = -yy - 1;
    if (yy >= H) yy = 2 * H - 1 - yy;
    a = a + w[t] * base[(yy * W + xx) * 4 + c];
  }
  mid[c][xx] = a;
  __syncthreads();
  float o = 0.0f;
  for (int t = 0; t <= 2 * GR; ++t) {
    int xq = xx - GR + t;
    if (xq < 0) xq = -xq - 1;
    if (xq >= W) xq = 2 * W - 1 - xq;
    o = o + w[t] * mid[c][xq];
  }
  ((float*)(pf + img * PIMG + y * PSTR + xx + KWIN))[c] = o;  // 4B store, no race
}

// ---------------- density: 8-wave producer/folder, exact sequential fold -------
// __expf (native v_exp_f32): ~1e-6 rel dens perturbation, self-consistent; pad
// sentinel still underflows to exact +0.0. Hybrid reads: dcu<31 from staged
// LDS row, dcu>=31 direct global (L1/L2-resident — same bits, same order).
template<int DB, int DE>
__device__ inline void produce_terms(const float4* __restrict__ rb,
                                     const float4* __restrict__ grow,
                                     float* __restrict__ tb,
                                     float4 fc, float sprf, int lane) {
#pragma clang fp contract(off)
#pragma unroll
  for (int dcu = DB; dcu < DE; ++dcu) {
    float4 nb = (dcu < 31) ? rb[lane + dcu] : grow[lane + dcu];
    float d0 = fc.x - nb.x, d1 = fc.y - nb.y, d2 = fc.z - nb.z;
    float d = (d0 * d0 + d1 * d1) + d2 * d2;
    float cdc = (float)((dcu - KWIN) * (dcu - KWIN));
    d = d + (sprf + cdc);                 // exact: both ints < 2^11, sum exact
    tb[dcu * 64 + lane] = __expf(-d * INV); // pad cols -> exact +0.0
  }
}

__global__ __launch_bounds__(512, 4)
void k_dens(float4* __restrict__ pf) {
#pragma clang fp contract(off)
  __shared__ float4 rowbuf[2][128];
  __shared__ float termbuf[2][61][64];
  int tid = threadIdx.x;
  int lane = tid & 63;
  int wave = tid >> 6;
  int b = blockIdx.x;                      // 512 blocks: img*256 + y*2 + tile
  int tile = b & 1, y = (b >> 1) & 127, img = b >> 8;
  int x0 = tile * 64;
  float4* fimg = pf + img * PIMG;
  float4 fc = fimg[y * PSTR + x0 + lane + KWIN];
  int ny0 = y - KWIN; if (ny0 < 0) ny0 = 0;
  int ny1 = y + KWIN; if (ny1 > H - 1) ny1 = H - 1;
  if (wave == 7) {
    const float4* row = fimg + ny0 * PSTR + x0;
    rowbuf[0][lane] = row[lane];
    rowbuf[0][lane + 64] = row[lane + 64];
  }
  __syncthreads();
  float acc = 0.0f;
  for (int ny = ny0; ny <= ny1; ++ny) {    // skipped rows: ref adds exact 0.0
    int kb = (ny - ny0) & 1;
    float4 p0, p1;
    bool pre = (wave == 7) && (ny < ny1);
    if (pre) {                             // issue prefetch early
      const float4* nrow = fimg + (ny + 1) * PSTR + x0;
      p0 = nrow[lane];
      p1 = nrow[lane + 64];
    }
    int dr = ny - y;
    float sprf = (float)(dr * dr);
    const float4* rb = rowbuf[kb];
    const float4* grow = fimg + ny * PSTR + x0;
    float* tb = &termbuf[kb][0][0];
    if      (wave == 1) produce_terms< 0,  9>(rb, grow, tb, fc, sprf, lane);
    else if (wave == 2) produce_terms< 9, 18>(rb, grow, tb, fc, sprf, lane);
    else if (wave == 3) produce_terms<18, 27>(rb, grow, tb, fc, sprf, lane);
    else if (wave == 4) produce_terms<27, 36>(rb, grow, tb, fc, sprf, lane);
    else if (wave == 5) produce_terms<36, 45>(rb, grow, tb, fc, sprf, lane);
    else if (wave == 6) produce_terms<45, 53>(rb, grow, tb, fc, sprf, lane);
    else if (wave == 7) produce_terms<53, 61>(rb, grow, tb, fc, sprf, lane);
    if (pre) {
      rowbuf[kb ^ 1][lane] = p0;
      rowbuf[kb ^ 1][lane + 64] = p1;
    }
    __syncthreads();
    if (wave == 0) {
#pragma unroll
      for (int dcu = 0; dcu < 61; ++dcu)
        acc = acc + termbuf[kb][dcu][lane];     // exact reference order
    }
  }
  if (wave == 0) fimg[y * PSTR + x0 + lane + KWIN].w = acc;
}

// ---------------- parent: half-split, dc-partitioned, packed-f32 SoA -----------
// Grid 1024: (img, y, tile, half). Rows staged into SoA LDS (xs/ys/zs/ws) so
// neighbor pairs (dcu, dcu+1) are ADJACENT floats -> clang emits v_pk_*_f32
// (2 f32/issue-slot, bit-identical per component) for the distance math.
// Conds stay scalar, low-dcu half updated first (exact scan-order tie-break);
// odd chunks get a scalar tail. Exactness: candidate q strictly increases in
// the reference's row-major scan order, so min over packed (d_bits<<32)|q keys
// reproduces first-wins under ANY partition. No fp reassociation.
template<int DB, int DE>
__device__ inline void par_pairs(const float* __restrict__ xs,
                                 const float* __restrict__ ys,
                                 const float* __restrict__ zs,
                                 const float* __restrict__ ws,
                                 int lane, f32x2 fcx, f32x2 fcy, f32x2 fcz,
                                 float dcen, float sprf, int qbase,
                                 float& bestd, int& bestp) {
#pragma clang fp contract(off)
#pragma unroll
  for (int d0 = DB; d0 + 1 < DE; d0 += 2) {
    int i0 = lane + d0;
    f32x2 nx = { xs[i0], xs[i0 + 1] };
    f32x2 nv = { ys[i0], ys[i0 + 1] };
    f32x2 nz = { zs[i0], zs[i0 + 1] };
    f32x2 nw = { ws[i0], ws[i0 + 1] };
    f32x2 dx = fcx - nx, dy = fcy - nv, dz = fcz - nz;
    f32x2 dd = (dx * dx + dy * dy) + dz * dz;
    f32x2 sp = { sprf + (float)((d0 - KWIN) * (d0 - KWIN)),
                 sprf + (float)((d0 + 1 - KWIN) * (d0 + 1 - KWIN)) };
    dd = dd + sp;                          // exact (ints < 2^11)
    int b0 = (nw.x > dcen) & (dd.x < bestd);
    bestd = b0 ? dd.x : bestd;
    bestp = b0 ? (qbase + d0 - KWIN) : bestp;
    int b1 = (nw.y > dcen) & (dd.y < bestd);
    bestd = b1 ? dd.y : bestd;
    bestp = b1 ? (qbase + d0 + 1 - KWIN) : bestp;
  }
  if constexpr ((DE - DB) & 1) {           // scalar tail
    constexpr int dcu = DE - 1;
    int i0 = lane + dcu;
    float nd = ws[i0];
    float d0 = fcx.x - xs[i0], d1 = fcy.x - ys[i0], d2 = fcz.x - zs[i0];
    float d = (d0 * d0 + d1 * d1) + d2 * d2;
    d = d + (sprf + (float)((dcu - KWIN) * (dcu - KWIN)));
    int bt = (nd > dcen) & (d < bestd);
    bestd = bt ? d : bestd;
    bestp = bt ? (qbase + dcu - KWIN) : bestp;
  }
}

__global__ __launch_bounds__(512, 4)
void k_par(const float4* __restrict__ pf, unsigned long long* __restrict__ pkeys) {
#pragma clang fp contract(off)
  __shared__ float soa[2][4][132];         // SoA row stage (x,y,z,w)[col]
  __shared__ unsigned long long m_k[8][64];
  int tid = threadIdx.x, lane = tid & 63, wave = tid >> 6;
  int b = blockIdx.x;                      // img*512 + y*4 + tile*2 + half
  int half = b & 1, tile = (b >> 1) & 1, y = (b >> 2) & 127, img = b >> 9;
  int x0 = tile * 64, x = x0 + lane;
  const float4* fimg = pf + img * PIMG;
  float4 fc = fimg[y * PSTR + x + KWIN];
  float dcen = fc.w;
  f32x2 fcx = { fc.x, fc.x }, fcy = { fc.y, fc.y }, fcz = { fc.z, fc.z };
  int ny0 = y - KWIN; if (ny0 < 0) ny0 = 0;
  int ny1 = y + KWIN; if (ny1 > H - 1) ny1 = H - 1;
  int nr = ny1 - ny0 + 1;
  int h0 = nr >> 1;                        // rows in half 0
  int hb = half ? (ny0 + h0) : ny0;
  int he = half ? (ny1 + 1) : (ny0 + h0);
  int sc = tid & 3, sj = tid >> 2;         // staging: thread -> (component, col)
  // stage first row: 512 threads load 512 consecutive floats (= 128 float4)
  soa[0][sc][sj] = ((const float*)(fimg + hb * PSTR + x0))[tid];
  __syncthreads();
  float bestd = __builtin_inff();
  int bestp = y * W + x;
  for (int ny = hb; ny < he; ++ny) {
    int kb = (ny - hb) & 1;
    float pval;
    bool pre = (ny + 1 < he);
    if (pre) pval = ((const float*)(fimg + (ny + 1) * PSTR + x0))[tid];
    int dr = ny - y;
    float sprf = (float)(dr * dr);
    int qbase = ny * W + x;
    const float* xs = soa[kb][0];
    const float* ys = soa[kb][1];
    const float* zs = soa[kb][2];
    const float* ws = soa[kb][3];
    if      (wave == 0) par_pairs< 0,  8>(xs, ys, zs, ws, lane, fcx, fcy, fcz, dcen, sprf, qbase, bestd, bestp);
    else if (wave == 1) par_pairs< 8, 16>(xs, ys, zs, ws, lane, fcx, fcy, fcz, dcen, sprf, qbase, bestd, bestp);
    else if (wave == 2) par_pairs<16, 24>(xs, ys, zs, ws, lane, fcx, fcy, fcz, dcen, sprf, qbase, bestd, bestp);
    else if (wave == 3) par_pairs<24, 31>(xs, ys, zs, ws, lane, fcx, fcy, fcz, dcen, sprf, qbase, bestd, bestp);
    else if (wave == 4) par_pairs<31, 39>(xs, ys, zs, ws, lane, fcx, fcy, fcz, dcen, sprf, qbase, bestd, bestp);
    else if (wave == 5) par_pairs<39, 47>(xs, ys, zs, ws, lane, fcx, fcy, fcz, dcen, sprf, qbase, bestd, bestp);
    else if (wave == 6) par_pairs<47, 54>(xs, ys, zs, ws, lane, fcx, fcy, fcz, dcen, sprf, qbase, bestd, bestp);
    else                par_pairs<54, 61>(xs, ys, zs, ws, lane, fcx, fcy, fcz, dcen, sprf, qbase, bestd, bestp);
    if (pre) soa[kb ^ 1][sc][sj] = pval;   // other buffer: no race this iter
    __syncthreads();                       // publish row ny+1
  }
  // pack (d, q): inf (no candidate) sorts above all finite d
  m_k[wave][lane] =
      ((unsigned long long)__float_as_uint(bestd) << 32) | (unsigned)bestp;
  __syncthreads();
  if (wave == 0) {
    unsigned long long k = m_k[0][lane];
#pragma unroll
    for (int w = 1; w < 8; ++w) {
      unsigned long long kw = m_k[w][lane];
      k = (kw < k) ? kw : k;
    }
    pkeys[half * (IMGS * NP) + img * NP + y * W + x] = k;
  }
}

// ---------------- finish: merge + root-chase + scan + label, all in LDS --------
// One block per image (1024 thr). parent (64KB) and root (64KB) live in LDS.
// Root flags = (parent[i]==i) — flattened-parent fixed points — computed in
// registers during merge. Root shortcut: lroot[j] transitions -1 -> final only
// (4B LDS writes are atomic units); racy reads give -1 (no shortcut, safe).
// After the chase barrier, lpar is dead and reused for the cumsum table.
__global__ __launch_bounds__(1024)
void k_finish(const unsigned long long* __restrict__ pkeys, int* __restrict__ out) {
  __shared__ int lpar[NP];                 // parent, then cumsum table
  __shared__ int lroot[NP];
  __shared__ int part[1024];
  int img = blockIdx.x;
  int t = threadIdx.x;
  int base = t * 16;
  const unsigned long long* pk0 = pkeys + img * NP;
  const unsigned long long* pk1 = pkeys + IMGS * NP + img * NP;
  int f[16];
#pragma unroll
  for (int j = 0; j < 16; ++j) {
    int i = base + j;
    unsigned long long k0 = pk0[i], k1 = pk1[i];
    unsigned long long k = (k0 < k1) ? k0 : k1;
    float bd = __uint_as_float((unsigned)(k >> 32));
    int par = (bd > 400.0f) ? i : (int)(k & 0xffffffffu);  // sqrt(d) > max_dist
    lpar[i] = par;
    lroot[i] = -1;
    f[j] = (par == i);
  }
  __syncthreads();
  int r16[16];
#pragma unroll 1
  for (int j = 0; j < 16; ++j) {
    int r = lpar[base + j];
#pragma unroll 1
    for (int it = 0; it < NP; ++it) {      // chains strictly increase density => acyclic
      int rr = lroot[r];
      int pr = lpar[r];
      if (rr >= 0) { r = rr; break; }
      if (pr == r) break;
      r = pr;
    }
    lroot[base + j] = r;
    r16[j] = r;
  }
  __syncthreads();                         // chases done; lpar reads finished
  int s = 0;
#pragma unroll
  for (int j = 0; j < 16; ++j) s += f[j];
  part[t] = s;
  __syncthreads();
  for (int off = 1; off < 1024; off <<= 1) {
    int add = (t >= off) ? part[t - off] : 0;
    __syncthreads();
    part[t] += add;
    __syncthreads();
  }
  int run = part[t] - s;                   // exclusive prefix of this chunk
#pragma unroll
  for (int j = 0; j < 16; ++j) { run += f[j]; lpar[base + j] = run; }  // cumsum
  __syncthreads();
  int* oimg = out + img * NP;
#pragma unroll
  for (int j = 0; j < 16; ++j) {
    int lab = lpar[r16[j]] - 1;
    oimg[base + j] = (lab < MAXSEG - 1) ? lab : (MAXSEG - 1);
  }
}

extern "C" void kernel_launch(void* const* d_in, const int* in_sizes, int n_in,
                              void* d_out, int out_size, void* d_ws, size_t ws_size,
                              hipStream_t stream) {
  const float* x = (const float*)d_in[0];
  int* out = (int*)d_out;
  char* ws = (char*)d_ws;

  // workspace layout (~1.31 MB). pkeys aliases bufL — bufL is dead after
  // k_blur, and k_par (which writes pkeys) runs after k_blur in-stream.
  float4* pf   = (float4*)(ws);                         // 2*24576*16 = 786432
  float4* bufL = (float4*)(ws + 786432);                // 524288 (lab output)
  unsigned long long* pkeys = (unsigned long long*)(ws + 786432);  // alias bufL, 524288

  const int total = IMGS * NP;                          // 32768
  const int ptotal = IMGS * PIMG;                       // 49152

  k_prep<<<(ptotal + 255) / 256, 256, 0, stream>>>(x, pf, bufL);
  k_blur<<<IMGS * H, 384, 0, stream>>>(bufL, pf);
  k_dens<<<512, 512, 0, stream>>>(pf);
  k_par<<<1024, 512, 0, stream>>>(pf, pkeys);
  k_finish<<<IMGS, 1024, 0, stream>>>(pkeys, out);
  (void)total;
}

// Round 17
// 202.348 us; speedup vs baseline: 1.1774x; 1.1774x over previous
//
#include <hip/hip_runtime.h>
#include <math.h>

static constexpr int IMGS = 2;
static constexpr int H = 128, W = 128;
static constexpr int NP = H * W;           // 16384
static constexpr int KWIN = 30;            // quickshift window radius (ceil(3*10))
static constexpr int GR = 20;              // gaussian radius int(4*5+0.5)
static constexpr float INV = 0.005f;       // 0.5 / (10*10)
static constexpr int MAXSEG = 40;

// padded feature layout: row stride 192 float4, cols [30,158) hold the image.
// float4 = (L, a, b, dens); pads = (1e6,1e6,1e6,-inf).
static constexpr int PSTR = 192;
static constexpr int PIMG = H * PSTR;      // 24576 float4 per image

typedef float f32x2 __attribute__((ext_vector_type(2)));

// ---------------- prep: pf sentinel fill + rgb2lab into bufL -------------------
__global__ void k_prep(const float* __restrict__ x, float4* __restrict__ pf,
                       float4* __restrict__ bufL) {
#pragma clang fp contract(off)
  int i = blockIdx.x * blockDim.x + threadIdx.x;
  if (i < IMGS * PIMG) pf[i] = make_float4(1e6f, 1e6f, 1e6f, -__builtin_inff());
  if (i >= IMGS * NP) return;
  int img = i / NP, p = i % NP;
  const float* base = x + img * 3 * NP;
  float rgb[3] = { base[p], base[NP + p], base[2 * NP + p] };
  float lin[3];
  for (int c = 0; c < 3; ++c) {
    float v = rgb[c];
    lin[c] = (v > 0.04045f) ? powf((v + 0.055f) / 1.055f, 2.4f) : (v / 12.92f);
  }
  const float M[3][3] = {{0.412453f, 0.357580f, 0.180423f},
                         {0.212671f, 0.715160f, 0.072169f},
                         {0.019334f, 0.119193f, 0.950227f}};
  const float wp[3] = {0.95047f, 1.0f, 1.08883f};
  float f[3];
  for (int j = 0; j < 3; ++j) {
    float s = lin[0] * M[j][0];
    s = s + lin[1] * M[j][1];
    s = s + lin[2] * M[j][2];
    float xyz = s / wp[j];
    f[j] = (xyz > 0.008856f) ? cbrtf(fmaxf(xyz, 1e-8f))
                             : (7.787f * xyz + (float)(16.0 / 116.0));
  }
  float L = 116.0f * f[1] - 16.0f;
  float a = 500.0f * (f[0] - f[1]);
  float b = 200.0f * (f[1] - f[2]);
  bufL[i] = make_float4(L, a, b, 0.0f);
}

// ---------------- fused separable gaussian (V then H), symmetric pad -----------
__global__ __launch_bounds__(384)
void k_blur(const float4* __restrict__ bufL, float4* __restrict__ pf) {
#pragma clang fp contract(off)
  __shared__ float w[2 * GR + 1];
  __shared__ float mid[3][128];
  if (threadIdx.x == 0) {
    double k[2 * GR + 1];
    double s = 0.0;
    for (int i = -GR; i <= GR; ++i) {
      double t = (double)i / 5.0;
      double v = exp(-0.5 * t * t);
      k[i + GR] = v;
      s += v;
    }
    for (int i = 0; i < 2 * GR + 1; ++i) w[i] = (float)(k[i] / s);
  }
  __syncthreads();
  int tid = threadIdx.x;
  int c = tid >> 7;                         // 0..2
  int xx = tid & 127;
  int b = blockIdx.x;                       // img*128 + y
  int y = b & 127, img = b >> 7;
  const float* base = (const float*)(bufL + img * NP);
  float a = 0.0f;
  for (int t = 0; t <= 2 * GR; ++t) {
    int yy = y - GR + t;
    if (yy < 0) yy = -yy - 1;
    if (yy >= H) yy = 2 * H - 1 - yy;
    a = a + w[t] * base[(yy * W + xx) * 4 + c];
  }
  mid[c][xx] = a;
  __syncthreads();
  float o = 0.0f;
  for (int t = 0; t <= 2 * GR; ++t) {
    int xq = xx - GR + t;
    if (xq < 0) xq = -xq - 1;
    if (xq >= W) xq = 2 * W - 1 - xq;
    o = o + w[t] * mid[c][xq];
  }
  ((float*)(pf + img * PIMG + y * PSTR + xx + KWIN))[c] = o;  // 4B store, no race
}

// ---------------- density: 8-wave producer/folder, exact sequential fold -------
// __expf (native v_exp_f32): ~1e-6 rel dens perturbation, self-consistent; pad
// sentinel still underflows to exact +0.0. Hybrid reads: dcu<31 from staged
// LDS row, dcu>=31 direct global (L1/L2-resident — same bits, same order).
template<int DB, int DE>
__device__ inline void produce_terms(const float4* __restrict__ rb,
                                     const float4* __restrict__ grow,
                                     float* __restrict__ tb,
                                     float4 fc, float sprf, int lane) {
#pragma clang fp contract(off)
#pragma unroll
  for (int dcu = DB; dcu < DE; ++dcu) {
    float4 nb = (dcu < 31) ? rb[lane + dcu] : grow[lane + dcu];
    float d0 = fc.x - nb.x, d1 = fc.y - nb.y, d2 = fc.z - nb.z;
    float d = (d0 * d0 + d1 * d1) + d2 * d2;
    float cdc = (float)((dcu - KWIN) * (dcu - KWIN));
    d = d + (sprf + cdc);                 // exact: both ints < 2^11, sum exact
    tb[dcu * 64 + lane] = __expf(-d * INV); // pad cols -> exact +0.0
  }
}

__global__ __launch_bounds__(512, 4)
void k_dens(float4* __restrict__ pf) {
#pragma clang fp contract(off)
  __shared__ float4 rowbuf[2][128];
  __shared__ float termbuf[2][61][64];
  int tid = threadIdx.x;
  int lane = tid & 63;
  int wave = tid >> 6;
  int b = blockIdx.x;                      // 512 blocks: img*256 + y*2 + tile
  int tile = b & 1, y = (b >> 1) & 127, img = b >> 8;
  int x0 = tile * 64;
  float4* fimg = pf + img * PIMG;
  float4 fc = fimg[y * PSTR + x0 + lane + KWIN];
  int ny0 = y - KWIN; if (ny0 < 0) ny0 = 0;
  int ny1 = y + KWIN; if (ny1 > H - 1) ny1 = H - 1;
  if (wave == 7) {
    const float4* row = fimg + ny0 * PSTR + x0;
    rowbuf[0][lane] = row[lane];
    rowbuf[0][lane + 64] = row[lane + 64];
  }
  __syncthreads();
  float acc = 0.0f;
  for (int ny = ny0; ny <= ny1; ++ny) {    // skipped rows: ref adds exact 0.0
    int kb = (ny - ny0) & 1;
    float4 p0, p1;
    bool pre = (wave == 7) && (ny < ny1);
    if (pre) {                             // issue prefetch early
      const float4* nrow = fimg + (ny + 1) * PSTR + x0;
      p0 = nrow[lane];
      p1 = nrow[lane + 64];
    }
    int dr = ny - y;
    float sprf = (float)(dr * dr);
    const float4* rb = rowbuf[kb];
    const float4* grow = fimg + ny * PSTR + x0;
    float* tb = &termbuf[kb][0][0];
    if      (wave == 1) produce_terms< 0,  9>(rb, grow, tb, fc, sprf, lane);
    else if (wave == 2) produce_terms< 9, 18>(rb, grow, tb, fc, sprf, lane);
    else if (wave == 3) produce_terms<18, 27>(rb, grow, tb, fc, sprf, lane);
    else if (wave == 4) produce_terms<27, 36>(rb, grow, tb, fc, sprf, lane);
    else if (wave == 5) produce_terms<36, 45>(rb, grow, tb, fc, sprf, lane);
    else if (wave == 6) produce_terms<45, 53>(rb, grow, tb, fc, sprf, lane);
    else if (wave == 7) produce_terms<53, 61>(rb, grow, tb, fc, sprf, lane);
    if (pre) {
      rowbuf[kb ^ 1][lane] = p0;
      rowbuf[kb ^ 1][lane + 64] = p1;
    }
    __syncthreads();
    if (wave == 0) {
#pragma unroll
      for (int dcu = 0; dcu < 61; ++dcu)
        acc = acc + termbuf[kb][dcu][lane];     // exact reference order
    }
  }
  if (wave == 0) fimg[y * PSTR + x0 + lane + KWIN].w = acc;
}

// ---------------- parent: half-split, dc-partitioned, packed-f32 SoA -----------
// (kept from R16 — not slower than R13's scalar version; this round's top-5
// will measure it cleanly.) Exactness: candidate q strictly increases in the
// reference's row-major scan order, so min over packed (d_bits<<32)|q keys
// reproduces first-wins under ANY partition. No fp reassociation; pk ops are
// bit-identical per component.
template<int DB, int DE>
__device__ inline void par_pairs(const float* __restrict__ xs,
                                 const float* __restrict__ ys,
                                 const float* __restrict__ zs,
                                 const float* __restrict__ ws,
                                 int lane, f32x2 fcx, f32x2 fcy, f32x2 fcz,
                                 float dcen, float sprf, int qbase,
                                 float& bestd, int& bestp) {
#pragma clang fp contract(off)
#pragma unroll
  for (int d0 = DB; d0 + 1 < DE; d0 += 2) {
    int i0 = lane + d0;
    f32x2 nx = { xs[i0], xs[i0 + 1] };
    f32x2 nv = { ys[i0], ys[i0 + 1] };
    f32x2 nz = { zs[i0], zs[i0 + 1] };
    f32x2 nw = { ws[i0], ws[i0 + 1] };
    f32x2 dx = fcx - nx, dy = fcy - nv, dz = fcz - nz;
    f32x2 dd = (dx * dx + dy * dy) + dz * dz;
    f32x2 sp = { sprf + (float)((d0 - KWIN) * (d0 - KWIN)),
                 sprf + (float)((d0 + 1 - KWIN) * (d0 + 1 - KWIN)) };
    dd = dd + sp;                          // exact (ints < 2^11)
    int b0 = (nw.x > dcen) & (dd.x < bestd);
    bestd = b0 ? dd.x : bestd;
    bestp = b0 ? (qbase + d0 - KWIN) : bestp;
    int b1 = (nw.y > dcen) & (dd.y < bestd);
    bestd = b1 ? dd.y : bestd;
    bestp = b1 ? (qbase + d0 + 1 - KWIN) : bestp;
  }
  if constexpr ((DE - DB) & 1) {           // scalar tail
    constexpr int dcu = DE - 1;
    int i0 = lane + dcu;
    float nd = ws[i0];
    float d0 = fcx.x - xs[i0], d1 = fcy.x - ys[i0], d2 = fcz.x - zs[i0];
    float d = (d0 * d0 + d1 * d1) + d2 * d2;
    d = d + (sprf + (float)((dcu - KWIN) * (dcu - KWIN)));
    int bt = (nd > dcen) & (d < bestd);
    bestd = bt ? d : bestd;
    bestp = bt ? (qbase + dcu - KWIN) : bestp;
  }
}

__global__ __launch_bounds__(512, 4)
void k_par(const float4* __restrict__ pf, unsigned long long* __restrict__ pkeys) {
#pragma clang fp contract(off)
  __shared__ float soa[2][4][132];         // SoA row stage (x,y,z,w)[col]
  __shared__ unsigned long long m_k[8][64];
  int tid = threadIdx.x, lane = tid & 63, wave = tid >> 6;
  int b = blockIdx.x;                      // img*512 + y*4 + tile*2 + half
  int half = b & 1, tile = (b >> 1) & 1, y = (b >> 2) & 127, img = b >> 9;
  int x0 = tile * 64, x = x0 + lane;
  const float4* fimg = pf + img * PIMG;
  float4 fc = fimg[y * PSTR + x + KWIN];
  float dcen = fc.w;
  f32x2 fcx = { fc.x, fc.x }, fcy = { fc.y, fc.y }, fcz = { fc.z, fc.z };
  int ny0 = y - KWIN; if (ny0 < 0) ny0 = 0;
  int ny1 = y + KWIN; if (ny1 > H - 1) ny1 = H - 1;
  int nr = ny1 - ny0 + 1;
  int h0 = nr >> 1;                        // rows in half 0
  int hb = half ? (ny0 + h0) : ny0;
  int he = half ? (ny1 + 1) : (ny0 + h0);
  int sc = tid & 3, sj = tid >> 2;         // staging: thread -> (component, col)
  soa[0][sc][sj] = ((const float*)(fimg + hb * PSTR + x0))[tid];
  __syncthreads();
  float bestd = __builtin_inff();
  int bestp = y * W + x;
  for (int ny = hb; ny < he; ++ny) {
    int kb = (ny - hb) & 1;
    float pval;
    bool pre = (ny + 1 < he);
    if (pre) pval = ((const float*)(fimg + (ny + 1) * PSTR + x0))[tid];
    int dr = ny - y;
    float sprf = (float)(dr * dr);
    int qbase = ny * W + x;
    const float* xs = soa[kb][0];
    const float* ys = soa[kb][1];
    const float* zs = soa[kb][2];
    const float* ws = soa[kb][3];
    if      (wave == 0) par_pairs< 0,  8>(xs, ys, zs, ws, lane, fcx, fcy, fcz, dcen, sprf, qbase, bestd, bestp);
    else if (wave == 1) par_pairs< 8, 16>(xs, ys, zs, ws, lane, fcx, fcy, fcz, dcen, sprf, qbase, bestd, bestp);
    else if (wave == 2) par_pairs<16, 24>(xs, ys, zs, ws, lane, fcx, fcy, fcz, dcen, sprf, qbase, bestd, bestp);
    else if (wave == 3) par_pairs<24, 31>(xs, ys, zs, ws, lane, fcx, fcy, fcz, dcen, sprf, qbase, bestd, bestp);
    else if (wave == 4) par_pairs<31, 39>(xs, ys, zs, ws, lane, fcx, fcy, fcz, dcen, sprf, qbase, bestd, bestp);
    else if (wave == 5) par_pairs<39, 47>(xs, ys, zs, ws, lane, fcx, fcy, fcz, dcen, sprf, qbase, bestd, bestp);
    else if (wave == 6) par_pairs<47, 54>(xs, ys, zs, ws, lane, fcx, fcy, fcz, dcen, sprf, qbase, bestd, bestp);
    else                par_pairs<54, 61>(xs, ys, zs, ws, lane, fcx, fcy, fcz, dcen, sprf, qbase, bestd, bestp);
    if (pre) soa[kb ^ 1][sc][sj] = pval;   // other buffer: no race this iter
    __syncthreads();                       // publish row ny+1
  }
  // pack (d, q): inf (no candidate) sorts above all finite d
  m_k[wave][lane] =
      ((unsigned long long)__float_as_uint(bestd) << 32) | (unsigned)bestp;
  __syncthreads();
  if (wave == 0) {
    unsigned long long k = m_k[0][lane];
#pragma unroll
    for (int w = 1; w < 8; ++w) {
      unsigned long long kw = m_k[w][lane];
      k = (kw < k) ? kw : k;
    }
    pkeys[half * (IMGS * NP) + img * NP + y * W + x] = k;
  }
}

// ---------------- merge halves -> parent, init root=-1 -------------------------
// (R15 epilogue restored verbatim — the R16 LDS fusion ran on 2 CUs with a
// serial ds_read latency chain: 68.6 µs vs ~15 µs for these three kernels.)
__global__ void k_merge(const unsigned long long* __restrict__ pkeys,
                        int* __restrict__ parent, int* __restrict__ root) {
  int i = blockIdx.x * blockDim.x + threadIdx.x;
  if (i >= IMGS * NP) return;
  unsigned long long k0 = pkeys[i], k1 = pkeys[IMGS * NP + i];
  unsigned long long k = (k0 < k1) ? k0 : k1;
  float bd = __uint_as_float((unsigned)(k >> 32));
  int p = i % NP;
  parent[i] = (bd > 400.0f) ? p : (int)(k & 0xffffffffu);  // sqrt(d) > max_dist
  root[i] = -1;                            // enables the k_root shortcut
}

// ---------------- root chase with published-root shortcut ----------------------
// root[j] only ever transitions -1 -> final root of j (single aligned 4B
// write), so a racy read returns -1 (no shortcut — safe) or the correct root.
__global__ void k_root(const int* __restrict__ parent, int* __restrict__ root) {
  int i = blockIdx.x * blockDim.x + threadIdx.x;
  if (i >= IMGS * NP) return;
  int img = i / NP, p = i % NP;
  const int* par = parent + img * NP;
  volatile int* rt = (volatile int*)(root + img * NP);
  int r = par[p];
#pragma unroll 1
  for (int it = 0; it < NP; ++it) {        // chains strictly increase density => acyclic
    int rr = rt[r];                        // published root of r (or -1)
    int pr = par[r];
    if (rr >= 0) { r = rr; break; }
    if (pr == r) break;
    r = pr;
  }
  root[i] = r;
}

// ---------------- scan of root flags + final labels (fused, coalesced) ---------
// Root flags derived from parent: pres[i] == (parent[i]==i) (flattened-parent
// fixed points). 1024 threads, int4 coalesced loads, register prefix + LDS scan.
__global__ __launch_bounds__(1024)
void k_scanlabel(const int* __restrict__ parent, const int* __restrict__ root,
                 int* __restrict__ cums, int* __restrict__ out) {
  __shared__ int part[1024];
  int img = blockIdx.x;
  int t = threadIdx.x;                     // 1024 threads x 16 elements
  const int* par = parent + img * NP;
  int base = t * 16;
  int f[16];
  const int4* p4 = (const int4*)(par + base);
#pragma unroll
  for (int j = 0; j < 4; ++j) {
    int4 v = p4[j];
    f[4 * j + 0] = (v.x == base + 4 * j + 0);
    f[4 * j + 1] = (v.y == base + 4 * j + 1);
    f[4 * j + 2] = (v.z == base + 4 * j + 2);
    f[4 * j + 3] = (v.w == base + 4 * j + 3);
  }
  int s = 0;
#pragma unroll
  for (int j = 0; j < 16; ++j) s += f[j];
  part[t] = s;
  __syncthreads();
  for (int off = 1; off < 1024; off <<= 1) {
    int add = (t >= off) ? part[t - off] : 0;
    __syncthreads();
    part[t] += add;
    __syncthreads();
  }
  int run = part[t] - s;                   // exclusive prefix of this chunk
  int* c = cums + img * NP;
#pragma unroll
  for (int j = 0; j < 16; ++j) { run += f[j]; c[base + j] = run; }
  __threadfence_block();
  __syncthreads();                         // block-visible global writes
  const int* rimg = root + img * NP;
  int* oimg = out + img * NP;
  for (int j = t; j < NP; j += 1024) {
    int lab = c[rimg[j]] - 1;
    oimg[j] = (lab < MAXSEG - 1) ? lab : (MAXSEG - 1);
  }
}

extern "C" void kernel_launch(void* const* d_in, const int* in_sizes, int n_in,
                              void* d_out, int out_size, void* d_ws, size_t ws_size,
                              hipStream_t stream) {
  const float* x = (const float*)d_in[0];
  int* out = (int*)d_out;
  char* ws = (char*)d_ws;

  // workspace layout (~1.75 MB). pkeys aliases bufL — bufL is dead after
  // k_blur, and k_par (which writes pkeys) runs after k_blur in-stream.
  float4* pf   = (float4*)(ws);                         // 2*24576*16 = 786432
  float4* bufL = (float4*)(ws + 786432);                // 524288 (lab output)
  unsigned long long* pkeys = (unsigned long long*)(ws + 786432);  // alias bufL, 524288
  int* parent  = (int*)(ws + 1310720);                  // 131072
  int* root    = (int*)(ws + 1441792);                  // 131072
  int* cums    = (int*)(ws + 1572864);                  // 131072

  const int total = IMGS * NP;                          // 32768
  const int ptotal = IMGS * PIMG;                       // 49152

  k_prep<<<(ptotal + 255) / 256, 256, 0, stream>>>(x, pf, bufL);
  k_blur<<<IMGS * H, 384, 0, stream>>>(bufL, pf);
  k_dens<<<512, 512, 0, stream>>>(pf);
  k_par<<<1024, 512, 0, stream>>>(pf, pkeys);
  k_merge<<<total / 256, 256, 0, stream>>>(pkeys, parent, root);
  k_root<<<total / 256, 256, 0, stream>>>(parent, root);
  k_scanlabel<<<IMGS, 1024, 0, stream>>>(parent, root, cums, out);
}